// Round 6
// baseline (480.071 us; speedup 1.0000x reference)
//
#include <hip/hip_runtime.h>

// out[B=16384, ONUM=512] = x[B, INUM=4096] @ wB[ONUM, INUM]^T, wB = (u < weight)
// v5: maximize independent barrier domains. 64x128 tile -> grid 1024 = 4 blocks/CU
// = 16 waves/CU from 4 INDEPENDENT 4-wave barrier domains (each SIMD hosts 4 waves
// of 4 different blocks: one block's barrier stall is hidden by the other three).
// LDS exactly 40 KB/block: A 1-buf [64][64] content-swizzled (reg-staged, swizzle
// both sides) + B 2-buf [128][64] content-swizzled (pre-swizzled gll source).
// Two barriers/step: bar1 = lgkm-only (A/B prefetch stays in flight), bar2 =
// __syncthreads. A-loads issued BEFORE B-glls so STOREA's implicit wait is
// vmcnt(4), leaving B flying through the store phase.

#define M_DIM 16384
#define N_DIM 512
#define K_DIM 4096
#define BM 64
#define BN 128
#define BK 64
#define NT (K_DIM / BK)          // 64
#define THREADS 256

using bf16x8 = __attribute__((ext_vector_type(8))) short;
using f32x4  = __attribute__((ext_vector_type(4))) float;

typedef __attribute__((address_space(1))) const void glb_cv;
typedef __attribute__((address_space(3))) void lds_v;

__device__ __forceinline__ unsigned short f2bf(float f) {
    union { float f; unsigned int u; } v;
    v.f = f;
    unsigned int r = v.u + 0x7FFFu + ((v.u >> 16) & 1u);   // RNE
    return (unsigned short)(r >> 16);
}

// ---------------- binarize: wB[o,k] = (u < weight) ? 1.0bf16 : 0 ----------------
__global__ __launch_bounds__(256) void binarize_kernel(const float* __restrict__ w,
                                                       const float* __restrict__ u,
                                                       unsigned short* __restrict__ wb) {
    int i = (blockIdx.x * 256 + threadIdx.x) * 4;
    float4 wv = *(const float4*)(w + i);
    float4 uv = *(const float4*)(u + i);
    ushort4 o;
    o.x = (uv.x < wv.x) ? 0x3F80u : 0u;
    o.y = (uv.y < wv.y) ? 0x3F80u : 0u;
    o.z = (uv.z < wv.z) ? 0x3F80u : 0u;
    o.w = (uv.w < wv.w) ? 0x3F80u : 0u;
    *(ushort4*)(wb + i) = o;
}

// ---------------- GEMM ----------------
// Content swizzle (both A and B, 16B-chunk granularity): physical chunk p of a
// 128B row holds logical chunk p ^ (row&7). Row base bank is always 0 (128B
// stride), so chunk index alone sets the bank quad; XOR with row&7 spreads 16
// same-chunk lanes over 8 quads (2-way = free, m136).
__global__ __launch_bounds__(THREADS, 4) void gemm_bin_kernel(const float* __restrict__ x,
                                                              const unsigned short* __restrict__ wb,
                                                              float* __restrict__ out) {
    __shared__ __attribute__((aligned(16))) unsigned short As[BM][64];        // 8 KB
    __shared__ __attribute__((aligned(16))) unsigned short Bs[2][BN][64];     // 32 KB

    const int t    = threadIdx.x;
    const int lane = t & 63;
    const int wave = t >> 6;                  // 0..3

    // XCD-chunked bijective swizzle: 1024 blocks, 128/XCD; bm-sharers (4 bn) adjacent.
    const int bid = blockIdx.x;
    const int swz = (bid & 7) * 128 + (bid >> 3);
    const int bn  = swz & 3;                  // N_DIM/BN = 4
    const int bm  = swz >> 2;                 // 0..255

    const int wm  = (wave >> 1) * 32;         // wave tile 32x64
    const int wn  = (wave & 1) * 64;
    const int khi = lane >> 4;                // 0..3
    const int l15 = lane & 15;
    const int sw  = l15 & 7;                  // row&7 for all fragment rows

    f32x4 acc[2][4] = {};

    const float* xg = x + (size_t)(bm * BM) * K_DIM;
    const unsigned short* wbg = wb + (size_t)(bn * BN) * K_DIM;

    float4 sa[4];                             // A staging regs (1 K-tile)

    // A: 64x64 fp32 = 1024 float4 chunks; 4/thread. ch = j*256+t -> row=ch>>4, colf=(ch&15)*4.
#define LOADA(k0)                                                                \
    _Pragma("unroll")                                                            \
    for (int j = 0; j < 4; ++j) {                                                \
        int ch = j * 256 + t;                                                    \
        sa[j] = *(const float4*)(xg + (size_t)(ch >> 4) * K_DIM + (k0) + (ch & 15) * 4); \
    }

    // STOREA: ushort4 (8B) at logical (row, col8=ch&15); phys chunk = (col8>>1)^(row&7).
#define STOREA                                                                   \
    _Pragma("unroll")                                                            \
    for (int j = 0; j < 4; ++j) {                                                \
        int ch   = j * 256 + t;                                                  \
        int row  = ch >> 4;                                                      \
        int col8 = ch & 15;                                                      \
        ushort4 h;                                                               \
        h.x = f2bf(sa[j].x); h.y = f2bf(sa[j].y);                                \
        h.z = f2bf(sa[j].z); h.w = f2bf(sa[j].w);                                \
        *(ushort4*)((char*)&As[0][0] + row * 128 +                               \
                    ((((col8 >> 1) ^ (row & 7)) << 4) | ((col8 & 1) << 3))) = h; \
    }

    // B: 128x64 bf16 = 16 KB = 1024 x 16B chunks; 4 gll/thread, linear LDS dest,
    // pre-swizzled global source (rule 21): phys chunk e&7 <- logical (e&7)^(row&7).
#define GLLB(b, k0)                                                              \
    _Pragma("unroll")                                                            \
    for (int c = 0; c < 4; ++c) {                                                \
        int e   = c * 256 + t;                                                   \
        int row = e >> 3;                                                        \
        int lc  = (e & 7) ^ (row & 7);                                           \
        const unsigned short* gsrc = wbg + (size_t)row * K_DIM + (k0) + lc * 8;  \
        unsigned short* ldst = (unsigned short*)&Bs[b][0][0] + (size_t)e * 8;    \
        __builtin_amdgcn_global_load_lds((glb_cv*)(const void*)gsrc,             \
                                         (lds_v*)(void*)ldst, 16, 0, 0);         \
    }

    // COMPUTE: 2 kk-substeps of K=32; per kk: 2 A frags + 4 B frags + 8 MFMA.
#define COMPUTE(bsc)                                                             \
    _Pragma("unroll")                                                            \
    for (int kk = 0; kk < 2; ++kk) {                                             \
        bf16x8 af[2], bfr[4];                                                    \
        int cc = (kk << 2) | khi;                                                \
        int pc = (cc ^ sw) << 4;                                                 \
        _Pragma("unroll") for (int i = 0; i < 2; ++i)                            \
            af[i] = *(const bf16x8*)((const char*)&As[0][0] +                    \
                                     (wm + i * 16 + l15) * 128 + pc);            \
        _Pragma("unroll") for (int j = 0; j < 4; ++j)                            \
            bfr[j] = *(const bf16x8*)((const char*)(bsc) +                       \
                                      (wn + j * 16 + l15) * 128 + pc);           \
        _Pragma("unroll") for (int i = 0; i < 2; ++i)                            \
            _Pragma("unroll") for (int j = 0; j < 4; ++j)                        \
                acc[i][j] = __builtin_amdgcn_mfma_f32_16x16x32_bf16(af[i], bfr[j], \
                                                                    acc[i][j], 0, 0, 0); \
    }

    // ---- prologue: stage tile 0 ----
    LOADA(0);
    GLLB(0, 0);
    STOREA;                        // in-order retirement: waits A (and thus nothing younger)
    __syncthreads();               // drains B(0) + lgkm

    // ---- main loop: t = 0..NT-2 ----
    int cur = 0;
    for (int kt = 0; kt < NT - 1; ++kt) {
        const int kn = (kt + 1) * BK;
        LOADA(kn);                 // A(t+1) x4 — oldest in queue
        GLLB(cur ^ 1, kn);         // B(t+1) x4 — younger
        COMPUTE(&Bs[cur][0][0]);
        // bar1: LDS reads done across waves; vmem prefetch stays in flight.
        asm volatile("s_waitcnt lgkmcnt(0)" ::: "memory");
        __builtin_amdgcn_s_barrier();
        STOREA;                    // implicit vmcnt(4): A retired, B(t+1) still flying
        __syncthreads();           // vmcnt(0)+lgkm(0)+barrier: B(t+1) landed (~1 step in flight)
        cur ^= 1;
    }
    // ---- final tile ----
    COMPUTE(&Bs[cur][0][0]);

    // ---- epilogue: C/D layout col=lane&15, row=(lane>>4)*4+reg ----
    const int col0 = bn * BN + wn + l15;
    const int row0 = bm * BM + wm + khi * 4;
#pragma unroll
    for (int i = 0; i < 2; ++i)
#pragma unroll
        for (int j = 0; j < 4; ++j)
#pragma unroll
            for (int r = 0; r < 4; ++r)
                out[(size_t)(row0 + i * 16 + r) * N_DIM + (col0 + j * 16)] = acc[i][j][r];
}

extern "C" void kernel_launch(void* const* d_in, const int* in_sizes, int n_in,
                              void* d_out, int out_size, void* d_ws, size_t ws_size,
                              hipStream_t stream) {
    const float* x = (const float*)d_in[0];
    const float* w = (const float*)d_in[1];
    const float* u = (const float*)d_in[2];
    float* out = (float*)d_out;
    unsigned short* wb = (unsigned short*)d_ws;   // 512*4096*2 = 4 MB

    binarize_kernel<<<dim3(N_DIM * K_DIM / 4 / 256), dim3(256), 0, stream>>>(w, u, wb);

    gemm_bin_kernel<<<dim3((M_DIM / BM) * (N_DIM / BN)), dim3(THREADS), 0, stream>>>(x, wb, out);
}